// Round 6
// baseline (120.555 us; speedup 1.0000x reference)
//
#include <hip/hip_runtime.h>
#include <cstdint>
#include <math.h>

#define BATCH 32
#define NPIX (512*512)        // 262144 pixels per batch
#define NB1 1024              // level-1 bins: tp bits [31:22]
#define NCOPY 4               // LDS sub-histogram copies (contention fix)
#define NBA 2048              // select level A: tp bits [21:11]
#define NBB 2048              // select level B: tp bits [10:0]
#define PXB 4096              // pixels per block (256 thr * 16 px)
#define CAP 131072            // candidate capacity per batch (32 MB total)
#define CNTSTRIDE 32          // one cache line (128B) per batch counter

struct State {
    int      pfx1[BATCH];            // selected 10-bit prefix (-1 if no fg)
    uint32_t krem[BATCH];            // rank among candidates (1-based)
    uint32_t cnt [BATCH*CNTSTRIDE];  // candidate count, line-padded
    float    thr [BATCH];            // final threshold
    double   I_low[BATCH];           // sum p     over fg with pfx <  pfx1
    double   U_low[BATCH];           // sum p^2+1 over same
    double   S_bg [BATCH];           // sum p^2 over background
    double   I_cnd[BATCH];           // sum p     over kept candidates
    double   U_cnd[BATCH];           // sum p^2+1 over kept candidates
};

// ---------------------------------------------------------------------------
// Pass 1: softmax, store val = fg ? -p : p, LDS level-1 histogram of tp bits.
// 4 interleaved sub-histogram copies break same-address atomic serialization.
// ---------------------------------------------------------------------------
__global__ __launch_bounds__(256)
void k_pass1(const float* __restrict__ logits,
             const float* __restrict__ target,
             const float* __restrict__ eps,
             float* __restrict__ val,
             uint32_t* __restrict__ hist1)
{
    __shared__ uint32_t lh[NB1 * NCOPY];   // lh[bin*NCOPY + copy], 16 KB
    const int tid = threadIdx.x;
    const int copy = tid & (NCOPY - 1);
    for (int i = tid; i < NB1 * NCOPY; i += 256) lh[i] = 0;
    __syncthreads();

    const int b = blockIdx.y;
    const size_t nbase = (size_t)b * NPIX;
    const size_t lbase = (size_t)b * 2 * NPIX;
    const int base = blockIdx.x * PXB;

    float4 L0[4], L1[4], T4[4], E4[4];
#pragma unroll
    for (int it = 0; it < 4; ++it) {
        const int i0 = base + (it * 256 + tid) * 4;
        L0[it] = *(const float4*)(logits + lbase + i0);
        L1[it] = *(const float4*)(logits + lbase + NPIX + i0);
        T4[it] = *(const float4*)(target + nbase + i0);
        E4[it] = *(const float4*)(eps    + nbase + i0);
    }

#pragma unroll
    for (int it = 0; it < 4; ++it) {
        const int i0 = base + (it * 256 + tid) * 4;
        float a0[4] = {L0[it].x, L0[it].y, L0[it].z, L0[it].w};
        float a1[4] = {L1[it].x, L1[it].y, L1[it].z, L1[it].w};
        float tv[4] = {T4[it].x, T4[it].y, T4[it].z, T4[it].w};
        float ev[4] = {E4[it].x, E4[it].y, E4[it].z, E4[it].w};
        float vv[4];
#pragma unroll
        for (int j = 0; j < 4; ++j) {
            float m  = fmaxf(a0[j], a1[j]);
            float e0 = expf(a0[j] - m);
            float e1 = expf(a1[j] - m);
            float p  = e1 / (e0 + e1);
            float tp = p * (tv[j] + ev[j]);
            bool fg  = (tv[j] == 1.0f);
            vv[j] = fg ? -p : p;
            if (fg)
                atomicAdd(&lh[(__float_as_uint(tp) >> 22) * NCOPY + copy], 1u);
        }
        *(float4*)(val + nbase + i0) = make_float4(vv[0], vv[1], vv[2], vv[3]);
    }

    __syncthreads();
    uint32_t* hb = hist1 + (size_t)b * NB1;
    for (int bin = tid; bin < NB1; bin += 256) {
        uint32_t v = lh[bin*NCOPY+0] + lh[bin*NCOPY+1] + lh[bin*NCOPY+2] + lh[bin*NCOPY+3];
        if (v) atomicAdd(hb + bin, v);
    }
}

// ---------------------------------------------------------------------------
// Scan level-1: pick 10-bit prefix containing rank k = max(1, n_fg/2).
// ---------------------------------------------------------------------------
__global__ __launch_bounds__(256)
void k_scan1(const uint32_t* __restrict__ hist1, State* st)
{
    const int b = blockIdx.x;
    const int t = threadIdx.x;
    const uint32_t* h = hist1 + (size_t)b * NB1;
    __shared__ uint32_t part[256];
    __shared__ int sBin; __shared__ uint32_t sRem;
    if (t == 0) { sBin = 0; sRem = 1; }

    const int g = NB1 / 256;   // 4
    uint32_t s = 0;
    for (int j = 0; j < g; ++j) s += h[t * g + j];
    part[t] = s;
    __syncthreads();
    for (int off = 1; off < 256; off <<= 1) {
        uint32_t v = (t >= off) ? part[t - off] : 0u;
        __syncthreads();
        part[t] += v;
        __syncthreads();
    }
    uint32_t incl = part[t], excl = incl - s;
    uint32_t total = part[255];
    if (total == 0) {
        if (t == 0) { st->pfx1[b] = -1; st->krem[b] = 0; st->thr[b] = INFINITY; }
        return;
    }
    uint32_t k = total / 2;
    if (k == 0) k = 1;

    if (excl < k && k <= incl) {
        uint32_t run = excl;
        for (int j = 0; j < g; ++j) {
            uint32_t c = h[t * g + j];
            if (run < k && k <= run + c) { sBin = t * g + j; sRem = k - run; break; }
            run += c;
        }
    }
    __syncthreads();
    if (t == 0) { st->pfx1[b] = sBin; st->krem[b] = sRem; }
}

// ---------------------------------------------------------------------------
// Fused pass: dice sums for sure-kept fg (pfx<pfx1) and bg; compact candidates
// (pfx==pfx1). ONE returning atomic per wave (padded per-batch counter).
// ---------------------------------------------------------------------------
__global__ __launch_bounds__(256)
void k_compact(const float* __restrict__ val,
               const float* __restrict__ eps,
               State* st, uint2* __restrict__ cand)
{
    const int b = blockIdx.y;
    const int tid = threadIdx.x;
    const int lane = tid & 63;
    const int pfx = st->pfx1[b];
    const size_t nbase = (size_t)b * NPIX;
    const int base = blockIdx.x * PXB;
    uint2* cb = cand + (size_t)b * CAP;

    float4 V4[4], E4[4];
#pragma unroll
    for (int it = 0; it < 4; ++it) {
        const int i0 = base + (it * 256 + tid) * 4;
        V4[it] = *(const float4*)(val + nbase + i0);
        E4[it] = *(const float4*)(eps + nbase + i0);
    }

    // Phase A: predicates + partial sums, all compile-time-indexed registers.
    uint32_t cb_[16], pb_[16];
    uint32_t predmask = 0;
    double Ilow = 0.0, Ulow = 0.0, Sbg = 0.0;
#pragma unroll
    for (int it = 0; it < 4; ++it) {
        float vv[4] = {V4[it].x, V4[it].y, V4[it].z, V4[it].w};
        float ev[4] = {E4[it].x, E4[it].y, E4[it].z, E4[it].w};
#pragma unroll
        for (int j = 0; j < 4; ++j) {
            const int idx = it * 4 + j;
            uint32_t vb = __float_as_uint(vv[j]);
            bool fg = (vb >> 31) != 0;
            float p = __uint_as_float(vb & 0x7FFFFFFFu);
            uint32_t bits = 0;
            if (fg) {
                float tp = p * (1.0f + ev[j]);
                bits = __float_as_uint(tp);
                int pf = (int)(bits >> 22);
                if (pf < pfx) {
                    Ilow += (double)p;
                    Ulow += (double)p * (double)p + 1.0;
                }
                if (pf == pfx) predmask |= (1u << idx);
            } else {
                Sbg += (double)p * (double)p;
            }
            cb_[idx] = bits;
            pb_[idx] = vb & 0x7FFFFFFFu;
        }
    }

    // One returning atomic per wave.
    uint32_t c = (uint32_t)__popc(predmask);
    uint32_t inc = c;
#pragma unroll
    for (int off = 1; off < 64; off <<= 1) {
        uint32_t v = __shfl_up(inc, off);
        if (lane >= off) inc += v;
    }
    uint32_t excl = inc - c;
    uint32_t wtotal = __shfl(inc, 63);
    uint32_t basec = 0;
    if (lane == 0 && wtotal) basec = atomicAdd(&st->cnt[b * CNTSTRIDE], wtotal);
    basec = __shfl(basec, 0);

    // Phase B: write candidates.
    uint32_t pos = basec + excl;
#pragma unroll
    for (int idx = 0; idx < 16; ++idx) {
        if ((predmask >> idx) & 1u) {
            if (pos < CAP) cb[pos] = make_uint2(cb_[idx], pb_[idx]);
            pos++;
        }
    }

    __shared__ double sI[256];
    __shared__ double sU[256];
    __shared__ double sB[256];
    sI[tid] = Ilow; sU[tid] = Ulow; sB[tid] = Sbg;
    __syncthreads();
    for (int off = 128; off > 0; off >>= 1) {
        if (tid < off) { sI[tid] += sI[tid+off]; sU[tid] += sU[tid+off]; sB[tid] += sB[tid+off]; }
        __syncthreads();
    }
    if (tid == 0) {
        atomicAdd(&st->I_low[b], sI[0]);
        atomicAdd(&st->U_low[b], sU[0]);
        atomicAdd(&st->S_bg[b],  sB[0]);
    }
}

// ---------------------------------------------------------------------------
// Select: one block per batch. Two-level LDS radix select over the candidate
// list (bits [21:11] then [10:0]) -> thr; then sum kept candidates.
// ---------------------------------------------------------------------------
#define SELECT_BIN(h, nb, k)                                                  \
    {                                                                         \
        const int g = (nb) / 256;                                             \
        uint32_t s = 0;                                                       \
        for (int j = 0; j < g; ++j) s += (h)[t * g + j];                      \
        part[t] = s;                                                          \
        __syncthreads();                                                      \
        for (int off = 1; off < 256; off <<= 1) {                             \
            uint32_t v = (t >= off) ? part[t - off] : 0u;                     \
            __syncthreads();                                                  \
            part[t] += v;                                                     \
            __syncthreads();                                                  \
        }                                                                     \
        uint32_t incl = part[t], excl = incl - s;                             \
        if (excl < (k) && (k) <= incl) {                                      \
            uint32_t run = excl;                                              \
            for (int j = 0; j < g; ++j) {                                     \
                uint32_t c = (h)[t * g + j];                                  \
                if (run < (k) && (k) <= run + c) {                            \
                    sBin = t * g + j;                                         \
                    sRem = (k) - run;                                         \
                    break;                                                    \
                }                                                             \
                run += c;                                                     \
            }                                                                 \
        }                                                                     \
        __syncthreads();                                                      \
    }

__global__ __launch_bounds__(256)
void k_select(State* st, const uint2* __restrict__ cand)
{
    const int b = blockIdx.x;
    const int t = threadIdx.x;
    const int pfx = st->pfx1[b];
    if (pfx < 0) return;                       // thr=INF, sums stay 0
    const uint32_t n = min(st->cnt[b * CNTSTRIDE], (uint32_t)CAP);
    const uint32_t k = st->krem[b];
    const uint2* cb = cand + (size_t)b * CAP;

    __shared__ uint32_t lh[NBA];
    __shared__ uint32_t part[256];
    __shared__ int sBin; __shared__ uint32_t sRem;
    if (t == 0) { sBin = 0; sRem = 1; }

    // level A: bits [21:11]
    for (int i = t; i < NBA; i += 256) lh[i] = 0;
    __syncthreads();
    for (uint32_t i = t; i < n; i += 256)
        atomicAdd(&lh[(cb[i].x >> 11) & (NBA - 1)], 1u);
    __syncthreads();
    SELECT_BIN(lh, NBA, k);
    const uint32_t binA = (uint32_t)sBin;
    const uint32_t remA = sRem;
    __syncthreads();

    // level B: bits [10:0] within binA
    for (int i = t; i < NBB; i += 256) lh[i] = 0;
    if (t == 0) { sBin = 0; sRem = 1; }
    __syncthreads();
    for (uint32_t i = t; i < n; i += 256) {
        uint32_t bits = cb[i].x;
        if (((bits >> 11) & (NBA - 1)) == binA)
            atomicAdd(&lh[bits & (NBB - 1)], 1u);
    }
    __syncthreads();
    SELECT_BIN(lh, NBB, remA);
    const uint32_t binB = (uint32_t)sBin;

    const uint32_t thr_bits = ((uint32_t)pfx << 22) | (binA << 11) | binB;

    // sums over kept candidates (tp <= thr, ties kept)
    double I = 0.0, U = 0.0;
    for (uint32_t i = t; i < n; i += 256) {
        uint2 cv = cb[i];
        if (cv.x <= thr_bits) {
            float p = __uint_as_float(cv.y);
            I += (double)p;
            U += (double)p * (double)p + 1.0;
        }
    }
    __shared__ double sI[256];
    __shared__ double sU[256];
    sI[t] = I; sU[t] = U;
    __syncthreads();
    for (int off = 128; off > 0; off >>= 1) {
        if (t < off) { sI[t] += sI[t+off]; sU[t] += sU[t+off]; }
        __syncthreads();
    }
    if (t == 0) {
        st->thr[b]   = __uint_as_float(thr_bits);
        st->I_cnd[b] = sI[0];
        st->U_cnd[b] = sU[0];
    }
}

__global__ void k_finalize(const State* __restrict__ st, float* __restrict__ out)
{
    const int t = threadIdx.x;
    double d = 0.0;
    if (t < BATCH) {
        double I = st->I_low[t] + st->I_cnd[t];
        double U = st->U_low[t] + st->U_cnd[t] + st->S_bg[t];
        d = (2.0 * I + 1e-5) / (U + 1e-5);
    }
    for (int off = 32; off > 0; off >>= 1) d += __shfl_down(d, off);
    if (t == 0) out[0] = (float)(1.0 - d / (double)BATCH);
}

// ---------------------------------------------------------------------------
extern "C" void kernel_launch(void* const* d_in, const int* in_sizes, int n_in,
                              void* d_out, int out_size, void* d_ws, size_t ws_size,
                              hipStream_t stream) {
    const float* logits = (const float*)d_in[0];
    const float* target = (const float*)d_in[1];
    const float* eps    = (const float*)d_in[2];
    float* out = (float*)d_out;

    char* ws = (char*)d_ws;
    const size_t h1B = (size_t)BATCH * NB1 * 4;            // 128 KB
    uint32_t* hist1 = (uint32_t*)ws;
    State* st = (State*)(ws + h1B);
    const size_t baseNeed = h1B + sizeof(State);

    size_t off = ((baseNeed + 255) / 256) * 256;
    uint2* cand = (uint2*)(ws + off);                      // 32 MB
    off += (size_t)BATCH * CAP * sizeof(uint2);
    float* val = (float*)(ws + off);                       // 32 MB

    // Zero histogram + state each call (graph-capture safe).
    hipMemsetAsync(ws, 0, baseNeed, stream);

    dim3 grid(NPIX / PXB, BATCH);   // 64 x 32 = 2048 blocks
    k_pass1  <<<grid, 256, 0, stream>>>(logits, target, eps, val, hist1);
    k_scan1  <<<BATCH, 256, 0, stream>>>(hist1, st);
    k_compact<<<grid, 256, 0, stream>>>(val, eps, st, cand);
    k_select <<<BATCH, 256, 0, stream>>>(st, cand);
    k_finalize<<<1, 64, 0, stream>>>(st, out);
}

// Round 7
// 87.343 us; speedup vs baseline: 1.3803x; 1.3803x over previous
//
#include <hip/hip_runtime.h>
#include <cstdint>
#include <math.h>

#define BATCH 32
#define NPIX (512*512)        // 262144 pixels per batch
#define NB1 1024              // level-1 bins: tp bits [31:22]
#define NCOPY 4               // LDS sub-histogram copies (contention fix)
#define NBA 2048              // select level A: tp bits [21:11]
#define NBB 2048              // select level B: tp bits [10:0]
#define PXB 4096              // pixels per block (256 thr * 16 px)
#define CAP 131072            // candidate capacity per batch (32 MB total)
#define CAP2 32768            // binA-candidate capacity per batch (8 MB total)
#define CNTSTRIDE 32          // one cache line (128B) per batch counter

struct State {
    int      pfx1[BATCH];            // selected 10-bit prefix (-1 if no fg)
    uint32_t krem[BATCH];            // rank within pfx1 bin (1-based)
    int      binA[BATCH];            // selected level-A bin
    uint32_t remA[BATCH];            // rank within binA (1-based)
    uint32_t cnt [BATCH*CNTSTRIDE];  // candidate count, line-padded
    uint32_t cnt2[BATCH*CNTSTRIDE];  // binA-candidate count, line-padded
    double   I_low[BATCH];           // sum p     over surely-kept fg
    double   U_low[BATCH];           // sum p^2+1 over same
    double   S_bg [BATCH];           // sum p^2 over background
    double   I_cnd[BATCH];           // sum p     over kept candidates
    double   U_cnd[BATCH];           // sum p^2+1 over kept candidates
};

// ---------------------------------------------------------------------------
// Pass 1: softmax, store val = fg ? -p : p, LDS level-1 histogram of tp bits.
// ---------------------------------------------------------------------------
__global__ __launch_bounds__(256)
void k_pass1(const float* __restrict__ logits,
             const float* __restrict__ target,
             const float* __restrict__ eps,
             float* __restrict__ val,
             uint32_t* __restrict__ hist1)
{
    __shared__ uint32_t lh[NB1 * NCOPY];   // lh[bin*NCOPY + copy], 16 KB
    const int tid = threadIdx.x;
    const int copy = tid & (NCOPY - 1);
    for (int i = tid; i < NB1 * NCOPY; i += 256) lh[i] = 0;
    __syncthreads();

    const int b = blockIdx.y;
    const size_t nbase = (size_t)b * NPIX;
    const size_t lbase = (size_t)b * 2 * NPIX;
    const int base = blockIdx.x * PXB;

    float4 L0[4], L1[4], T4[4], E4[4];
#pragma unroll
    for (int it = 0; it < 4; ++it) {
        const int i0 = base + (it * 256 + tid) * 4;
        L0[it] = *(const float4*)(logits + lbase + i0);
        L1[it] = *(const float4*)(logits + lbase + NPIX + i0);
        T4[it] = *(const float4*)(target + nbase + i0);
        E4[it] = *(const float4*)(eps    + nbase + i0);
    }

#pragma unroll
    for (int it = 0; it < 4; ++it) {
        const int i0 = base + (it * 256 + tid) * 4;
        float a0[4] = {L0[it].x, L0[it].y, L0[it].z, L0[it].w};
        float a1[4] = {L1[it].x, L1[it].y, L1[it].z, L1[it].w};
        float tv[4] = {T4[it].x, T4[it].y, T4[it].z, T4[it].w};
        float ev[4] = {E4[it].x, E4[it].y, E4[it].z, E4[it].w};
        float vv[4];
#pragma unroll
        for (int j = 0; j < 4; ++j) {
            float m  = fmaxf(a0[j], a1[j]);
            float e0 = expf(a0[j] - m);
            float e1 = expf(a1[j] - m);
            float p  = e1 / (e0 + e1);
            float tp = p * (tv[j] + ev[j]);
            bool fg  = (tv[j] == 1.0f);
            vv[j] = fg ? -p : p;
            if (fg)
                atomicAdd(&lh[(__float_as_uint(tp) >> 22) * NCOPY + copy], 1u);
        }
        *(float4*)(val + nbase + i0) = make_float4(vv[0], vv[1], vv[2], vv[3]);
    }

    __syncthreads();
    uint32_t* hb = hist1 + (size_t)b * NB1;
    for (int bin = tid; bin < NB1; bin += 256) {
        uint32_t v = lh[bin*NCOPY+0] + lh[bin*NCOPY+1] + lh[bin*NCOPY+2] + lh[bin*NCOPY+3];
        if (v) atomicAdd(hb + bin, v);
    }
}

// ---------------------------------------------------------------------------
// Scan level-1: pick 10-bit prefix containing rank k = max(1, n_fg/2).
// ---------------------------------------------------------------------------
__global__ __launch_bounds__(256)
void k_scan1(const uint32_t* __restrict__ hist1, State* st)
{
    const int b = blockIdx.x;
    const int t = threadIdx.x;
    const uint32_t* h = hist1 + (size_t)b * NB1;
    __shared__ uint32_t part[256];
    __shared__ int sBin; __shared__ uint32_t sRem;
    if (t == 0) { sBin = 0; sRem = 1; }

    const int g = NB1 / 256;   // 4
    uint32_t s = 0;
    for (int j = 0; j < g; ++j) s += h[t * g + j];
    part[t] = s;
    __syncthreads();
    for (int off = 1; off < 256; off <<= 1) {
        uint32_t v = (t >= off) ? part[t - off] : 0u;
        __syncthreads();
        part[t] += v;
        __syncthreads();
    }
    uint32_t incl = part[t], excl = incl - s;
    uint32_t total = part[255];
    if (total == 0) {
        if (t == 0) { st->pfx1[b] = -1; st->krem[b] = 0; }
        return;
    }
    uint32_t k = total / 2;
    if (k == 0) k = 1;

    if (excl < k && k <= incl) {
        uint32_t run = excl;
        for (int j = 0; j < g; ++j) {
            uint32_t c = h[t * g + j];
            if (run < k && k <= run + c) { sBin = t * g + j; sRem = k - run; break; }
            run += c;
        }
    }
    __syncthreads();
    if (t == 0) { st->pfx1[b] = sBin; st->krem[b] = sRem; }
}

// ---------------------------------------------------------------------------
// Fused pass: dice sums for sure-kept fg (pfx<pfx1) and bg; compact candidates
// (pfx==pfx1) + build their level-A histogram (bits [21:11]).
// ---------------------------------------------------------------------------
__global__ __launch_bounds__(256)
void k_compact(const float* __restrict__ val,
               const float* __restrict__ eps,
               State* st, uint2* __restrict__ cand,
               uint32_t* __restrict__ histA)
{
    const int b = blockIdx.y;
    const int tid = threadIdx.x;
    const int lane = tid & 63;
    const int pfx = st->pfx1[b];
    const size_t nbase = (size_t)b * NPIX;
    const int base = blockIdx.x * PXB;
    uint2* cb = cand + (size_t)b * CAP;

    __shared__ uint32_t lhA[NBA];          // 8 KB
    for (int i = tid; i < NBA; i += 256) lhA[i] = 0;
    __syncthreads();

    float4 V4[4], E4[4];
#pragma unroll
    for (int it = 0; it < 4; ++it) {
        const int i0 = base + (it * 256 + tid) * 4;
        V4[it] = *(const float4*)(val + nbase + i0);
        E4[it] = *(const float4*)(eps + nbase + i0);
    }

    // Phase A: predicates + partial sums, all compile-time-indexed registers.
    uint32_t cb_[16], pb_[16];
    uint32_t predmask = 0;
    double Ilow = 0.0, Ulow = 0.0, Sbg = 0.0;
#pragma unroll
    for (int it = 0; it < 4; ++it) {
        float vv[4] = {V4[it].x, V4[it].y, V4[it].z, V4[it].w};
        float ev[4] = {E4[it].x, E4[it].y, E4[it].z, E4[it].w};
#pragma unroll
        for (int j = 0; j < 4; ++j) {
            const int idx = it * 4 + j;
            uint32_t vb = __float_as_uint(vv[j]);
            bool fg = (vb >> 31) != 0;
            float p = __uint_as_float(vb & 0x7FFFFFFFu);
            uint32_t bits = 0;
            if (fg) {
                float tp = p * (1.0f + ev[j]);
                bits = __float_as_uint(tp);
                int pf = (int)(bits >> 22);
                if (pf < pfx) {
                    Ilow += (double)p;
                    Ulow += (double)p * (double)p + 1.0;
                }
                if (pf == pfx) {
                    predmask |= (1u << idx);
                    atomicAdd(&lhA[(bits >> 11) & (NBA - 1)], 1u);
                }
            } else {
                Sbg += (double)p * (double)p;
            }
            cb_[idx] = bits;
            pb_[idx] = vb & 0x7FFFFFFFu;
        }
    }

    // One returning atomic per wave for the candidate list.
    uint32_t c = (uint32_t)__popc(predmask);
    uint32_t inc = c;
#pragma unroll
    for (int off = 1; off < 64; off <<= 1) {
        uint32_t v = __shfl_up(inc, off);
        if (lane >= off) inc += v;
    }
    uint32_t excl = inc - c;
    uint32_t wtotal = __shfl(inc, 63);
    uint32_t basec = 0;
    if (lane == 0 && wtotal) basec = atomicAdd(&st->cnt[b * CNTSTRIDE], wtotal);
    basec = __shfl(basec, 0);

    uint32_t pos = basec + excl;
#pragma unroll
    for (int idx = 0; idx < 16; ++idx) {
        if ((predmask >> idx) & 1u) {
            if (pos < CAP) cb[pos] = make_uint2(cb_[idx], pb_[idx]);
            pos++;
        }
    }

    __syncthreads();
    uint32_t* hA = histA + (size_t)b * NBA;
    for (int i = tid; i < NBA; i += 256) {
        uint32_t v = lhA[i];
        if (v) atomicAdd(hA + i, v);
    }

    __shared__ double sI[256];
    __shared__ double sU[256];
    __shared__ double sB[256];
    sI[tid] = Ilow; sU[tid] = Ulow; sB[tid] = Sbg;
    __syncthreads();
    for (int off = 128; off > 0; off >>= 1) {
        if (tid < off) { sI[tid] += sI[tid+off]; sU[tid] += sU[tid+off]; sB[tid] += sB[tid+off]; }
        __syncthreads();
    }
    if (tid == 0) {
        atomicAdd(&st->I_low[b], sI[0]);
        atomicAdd(&st->U_low[b], sU[0]);
        atomicAdd(&st->S_bg[b],  sB[0]);
    }
}

// ---------------------------------------------------------------------------
#define SELECT_BIN(h, nb, k)                                                  \
    {                                                                         \
        const int g = (nb) / 256;                                             \
        uint32_t s = 0;                                                       \
        for (int j = 0; j < g; ++j) s += (h)[t * g + j];                      \
        part[t] = s;                                                          \
        __syncthreads();                                                      \
        for (int off = 1; off < 256; off <<= 1) {                             \
            uint32_t v = (t >= off) ? part[t - off] : 0u;                     \
            __syncthreads();                                                  \
            part[t] += v;                                                     \
            __syncthreads();                                                  \
        }                                                                     \
        uint32_t incl = part[t], excl = incl - s;                             \
        if (excl < (k) && (k) <= incl) {                                      \
            uint32_t run = excl;                                              \
            for (int j = 0; j < g; ++j) {                                     \
                uint32_t c = (h)[t * g + j];                                  \
                if (run < (k) && (k) <= run + c) {                            \
                    sBin = t * g + j;                                         \
                    sRem = (k) - run;                                         \
                    break;                                                    \
                }                                                             \
                run += c;                                                     \
            }                                                                 \
        }                                                                     \
        __syncthreads();                                                      \
    }

// Scan level-A histogram -> binA, remA. One small block per batch.
__global__ __launch_bounds__(256)
void k_scanA(const uint32_t* __restrict__ histA, State* st)
{
    const int b = blockIdx.x;
    const int t = threadIdx.x;
    if (st->pfx1[b] < 0) return;
    const uint32_t* h = histA + (size_t)b * NBA;
    const uint32_t k = st->krem[b];
    __shared__ uint32_t part[256];
    __shared__ int sBin; __shared__ uint32_t sRem;
    if (t == 0) { sBin = 0; sRem = 1; }
    __syncthreads();
    SELECT_BIN(h, NBA, k);
    if (t == 0) { st->binA[b] = sBin; st->remA[b] = sRem; }
}

// ---------------------------------------------------------------------------
// Level-B pass over candidates (parallel): sub<binA -> kept sums; sub==binA ->
// LDS histB + compact into tiny cand2 list.
// ---------------------------------------------------------------------------
__global__ __launch_bounds__(256)
void k_histB(State* st, const uint2* __restrict__ cand,
             uint32_t* __restrict__ histB, uint2* __restrict__ cand2)
{
    const int b = blockIdx.y;
    const int t = threadIdx.x;
    if (st->pfx1[b] < 0) return;
    const uint32_t binA = (uint32_t)st->binA[b];
    const uint32_t n = min(st->cnt[b * CNTSTRIDE], (uint32_t)CAP);
    const uint2* cb = cand + (size_t)b * CAP;
    uint2* c2 = cand2 + (size_t)b * CAP2;

    __shared__ uint32_t lhB[NBB];          // 8 KB
    for (int i = t; i < NBB; i += 256) lhB[i] = 0;
    __syncthreads();

    double I = 0.0, U = 0.0;
    for (uint32_t i = blockIdx.x * 256 + t; i < n; i += gridDim.x * 256) {
        uint2 cv = cb[i];
        uint32_t sub = (cv.x >> 11) & (NBA - 1);
        if (sub < binA) {
            float p = __uint_as_float(cv.y);
            I += (double)p;
            U += (double)p * (double)p + 1.0;
        } else if (sub == binA) {
            atomicAdd(&lhB[cv.x & (NBB - 1)], 1u);
            uint32_t pos = atomicAdd(&st->cnt2[b * CNTSTRIDE], 1u);
            if (pos < CAP2) c2[pos] = cv;
        }
    }

    __syncthreads();
    uint32_t* hB = histB + (size_t)b * NBB;
    for (int i = t; i < NBB; i += 256) {
        uint32_t v = lhB[i];
        if (v) atomicAdd(hB + i, v);
    }

    __shared__ double sI[256];
    __shared__ double sU[256];
    sI[t] = I; sU[t] = U;
    __syncthreads();
    for (int off = 128; off > 0; off >>= 1) {
        if (t < off) { sI[t] += sI[t+off]; sU[t] += sU[t+off]; }
        __syncthreads();
    }
    if (t == 0) {
        atomicAdd(&st->I_cnd[b], sI[0]);
        atomicAdd(&st->U_cnd[b], sU[0]);
    }
}

// ---------------------------------------------------------------------------
// Scan level-B histogram -> binB -> thr; sum the tiny cand2 list <= thr.
// ---------------------------------------------------------------------------
__global__ __launch_bounds__(256)
void k_scanB(State* st, const uint2* __restrict__ cand2)
{
    const int b = blockIdx.x;
    const int t = threadIdx.x;
    const int pfx = st->pfx1[b];
    if (pfx < 0) return;
    const uint32_t* h = (const uint32_t*)nullptr; (void)h;
    const uint32_t k = st->remA[b];
    const uint32_t binA = (uint32_t)st->binA[b];
    const uint2* c2 = cand2 + (size_t)b * CAP2;
    const uint32_t n2 = min(st->cnt2[b * CNTSTRIDE], (uint32_t)CAP2);

    extern __shared__ uint32_t dynamic_smem[];  // unused; keep static below
    __shared__ uint32_t part[256];
    __shared__ int sBin; __shared__ uint32_t sRem;
    if (t == 0) { sBin = 0; sRem = 1; }
    __syncthreads();
    const uint32_t* hB = st->pfx1 ? nullptr : nullptr; (void)hB;
    // histB pointer passed via cand2 trick is ugly; recompute via offset:
    // (we pass histB as a second param instead)
    (void)k; (void)binA; (void)c2; (void)n2;
}

// real scanB (separate to keep signature clean)
__global__ __launch_bounds__(256)
void k_scanB2(State* st, const uint32_t* __restrict__ histB,
              const uint2* __restrict__ cand2)
{
    const int b = blockIdx.x;
    const int t = threadIdx.x;
    const int pfx = st->pfx1[b];
    if (pfx < 0) return;
    const uint32_t* h = histB + (size_t)b * NBB;
    const uint32_t k = st->remA[b];
    const uint32_t binA = (uint32_t)st->binA[b];
    const uint2* c2 = cand2 + (size_t)b * CAP2;
    const uint32_t n2 = min(st->cnt2[b * CNTSTRIDE], (uint32_t)CAP2);

    __shared__ uint32_t part[256];
    __shared__ int sBin; __shared__ uint32_t sRem;
    if (t == 0) { sBin = 0; sRem = 1; }
    __syncthreads();
    SELECT_BIN(h, NBB, k);
    const uint32_t binB = (uint32_t)sBin;
    const uint32_t thr_bits = ((uint32_t)pfx << 22) | (binA << 11) | binB;

    double I = 0.0, U = 0.0;
    for (uint32_t i = t; i < n2; i += 256) {
        uint2 cv = c2[i];
        if (cv.x <= thr_bits) {
            float p = __uint_as_float(cv.y);
            I += (double)p;
            U += (double)p * (double)p + 1.0;
        }
    }
    __shared__ double sI[256];
    __shared__ double sU[256];
    sI[t] = I; sU[t] = U;
    __syncthreads();
    for (int off = 128; off > 0; off >>= 1) {
        if (t < off) { sI[t] += sI[t+off]; sU[t] += sU[t+off]; }
        __syncthreads();
    }
    if (t == 0) {
        atomicAdd(&st->I_cnd[b], sI[0]);
        atomicAdd(&st->U_cnd[b], sU[0]);
    }
}

__global__ void k_finalize(const State* __restrict__ st, float* __restrict__ out)
{
    const int t = threadIdx.x;
    double d = 0.0;
    if (t < BATCH) {
        double I = st->I_low[t] + st->I_cnd[t];
        double U = st->U_low[t] + st->U_cnd[t] + st->S_bg[t];
        d = (2.0 * I + 1e-5) / (U + 1e-5);
    }
    for (int off = 32; off > 0; off >>= 1) d += __shfl_down(d, off);
    if (t == 0) out[0] = (float)(1.0 - d / (double)BATCH);
}

// ---------------------------------------------------------------------------
extern "C" void kernel_launch(void* const* d_in, const int* in_sizes, int n_in,
                              void* d_out, int out_size, void* d_ws, size_t ws_size,
                              hipStream_t stream) {
    const float* logits = (const float*)d_in[0];
    const float* target = (const float*)d_in[1];
    const float* eps    = (const float*)d_in[2];
    float* out = (float*)d_out;

    char* ws = (char*)d_ws;
    const size_t h1B = (size_t)BATCH * NB1 * 4;            // 128 KB
    const size_t hAB = (size_t)BATCH * NBA * 4;            // 256 KB
    const size_t hBB = (size_t)BATCH * NBB * 4;            // 256 KB
    uint32_t* hist1 = (uint32_t*)ws;
    uint32_t* histA = (uint32_t*)(ws + h1B);
    uint32_t* histB = (uint32_t*)(ws + h1B + hAB);
    State* st = (State*)(ws + h1B + hAB + hBB);
    const size_t baseNeed = h1B + hAB + hBB + sizeof(State);

    size_t off = ((baseNeed + 255) / 256) * 256;
    uint2* cand = (uint2*)(ws + off);                      // 32 MB
    off += (size_t)BATCH * CAP * sizeof(uint2);
    uint2* cand2 = (uint2*)(ws + off);                     // 8 MB
    off += (size_t)BATCH * CAP2 * sizeof(uint2);
    float* val = (float*)(ws + off);                       // 32 MB

    // Zero histograms + state each call (graph-capture safe).
    hipMemsetAsync(ws, 0, baseNeed, stream);

    dim3 grid(NPIX / PXB, BATCH);   // 64 x 32 = 2048 blocks
    k_pass1  <<<grid, 256, 0, stream>>>(logits, target, eps, val, hist1);
    k_scan1  <<<BATCH, 256, 0, stream>>>(hist1, st);
    k_compact<<<grid, 256, 0, stream>>>(val, eps, st, cand, histA);
    k_scanA  <<<BATCH, 256, 0, stream>>>(histA, st);
    k_histB  <<<dim3(16, BATCH), 256, 0, stream>>>(st, cand, histB, cand2);
    k_scanB2 <<<BATCH, 256, 0, stream>>>(st, histB, cand2);
    k_finalize<<<1, 64, 0, stream>>>(st, out);
}